// Round 5
// baseline (3118.550 us; speedup 1.0000x reference)
//
#include <hip/hip_runtime.h>

#define NB 16
#define NN 307
#define NI 11

typedef __attribute__((ext_vector_type(8))) short bf16x8;
typedef __attribute__((ext_vector_type(4))) float f32x4;

// ws offsets in FLOAT units
#define OFF_ABF    0u          // 320x320 bf16 = 51200 fl
#define OFF_AGCWT  51200u      // 307*64*128 bf16 = 1257472 fl
#define OFF_AGCB   1308672u    // 307*64 f32 -> pad 20480
#define OFF_WT     1329152u    // 4096*64 bf16 = 131072 fl
#define OFF_H      1460224u    // each state: 16*307*64 = 314368 fl
#define OFF_Z      1774592u
#define OFF_KH     2088960u
#define OFF_KZ     2403328u
#define OFF_ACCH   2717696u
#define OFF_ACCZ   3032064u
#define OFF_XBF    3346432u    // 320*16*64 bf16 = 163840 fl
#define OFF_XGBF   3510272u    // 320*16*64 bf16 = 163840 fl
#define OFF_XT     3674112u    // 16*64*320 bf16 = 163840 fl ; end 3837952 fl = 15.4 MB

__device__ __forceinline__ float tanh_fast(float x){
    float e = __expf(2.0f * x);
    return 1.0f - 2.0f * __builtin_amdgcn_rcpf(e + 1.0f);
}
__device__ __forceinline__ unsigned short f2bf(float f){
    unsigned u = __builtin_bit_cast(unsigned, f);
    unsigned r = u + 0x7FFFu + ((u >> 16) & 1u);
    return (unsigned short)(r >> 16);
}

// ---------- precompute ----------

// Abf[n][m] = bf16(softmax(relu(gE gE^T))) padded to 320x320 with zeros
__global__ void kA(const float* __restrict__ gE, unsigned short* __restrict__ Abf){
    int n = blockIdx.x;            // grid 320, 64 threads
    int lane = threadIdx.x;
    if (n >= NN){
#pragma unroll
        for (int ii = 0; ii < 5; ii++) Abf[n*320 + lane + 64*ii] = 0;
        return;
    }
    float en[8];
#pragma unroll
    for (int d = 0; d < 8; d++) en[d] = gE[n*8 + d];
    float vals[5];
    float mx = -1e30f;
#pragma unroll
    for (int ii = 0; ii < 5; ii++){
        int m = lane + 64*ii;
        float v = -1e30f;
        if (m < NN){
            float a = 0.f;
#pragma unroll
            for (int d = 0; d < 8; d++) a += en[d] * gE[m*8 + d];
            v = fmaxf(a, 0.f);
        }
        vals[ii] = v;
        mx = fmaxf(mx, v);
    }
#pragma unroll
    for (int off = 32; off >= 1; off >>= 1) mx = fmaxf(mx, __shfl_xor(mx, off, 64));
    float s = 0.f;
#pragma unroll
    for (int ii = 0; ii < 5; ii++){
        int m = lane + 64*ii;
        if (m < NN){ vals[ii] = __expf(vals[ii] - mx); s += vals[ii]; }
    }
#pragma unroll
    for (int off = 32; off >= 1; off >>= 1) s += __shfl_xor(s, off, 64);
    float inv = 1.f / s;
#pragma unroll
    for (int ii = 0; ii < 5; ii++){
        int m = lane + 64*ii;
        unsigned short v = 0;
        if (m < NN) v = f2bf(vals[ii] * inv);
        Abf[n*320 + m] = v;
    }
}

// agcWt[n][o][k] bf16, k = kk*64+i in [0,128)
__global__ __launch_bounds__(256) void kAgcWT(const float* __restrict__ gE,
                                              const float* __restrict__ gWpool,
                                              unsigned short* __restrict__ agcWt){
    __shared__ float t[128*65];
    int tid = threadIdx.x;
    int n = blockIdx.x;            // grid 307
    float ge[8];
#pragma unroll
    for (int d = 0; d < 8; d++) ge[d] = gE[n*8 + d];
    for (int it = 0; it < 32; it++){
        int e = it*256 + tid;      // [0,8192)
        int o = e & 63, i = (e >> 6) & 63, kk = e >> 12;
        float acc = 0.f;
#pragma unroll
        for (int d = 0; d < 8; d++) acc += ge[d] * gWpool[((size_t)(d*2 + kk)*64 + i)*64 + o];
        t[(kk*64 + i)*65 + o] = acc;
    }
    __syncthreads();
    for (int it = 0; it < 32; it++){
        int e = it*256 + tid;
        int k = e & 127, o = e >> 7;
        agcWt[((size_t)n*64 + o)*128 + k] = f2bf(t[k*65 + o]);
    }
}

__global__ void kAgcB(const float* __restrict__ gE, const float* __restrict__ gbpool,
                      float* __restrict__ agcb){
    int gid = blockIdx.x*256 + threadIdx.x;
    if (gid >= NN*64) return;
    int o = gid & 63;
    int n = gid >> 6;
    float acc = 0.f;
#pragma unroll
    for (int d = 0; d < 8; d++) acc += gE[n*8 + d] * gbpool[d*64 + o];
    agcb[gid] = acc;
}

// Wtbf[col][k] bf16 (transpose of WgOut[k][col])
__global__ __launch_bounds__(256) void kWt(const float* __restrict__ WgOut,
                                           unsigned short* __restrict__ Wtbf){
    __shared__ float t[64*65];
    int tid = threadIdx.x;
    int c0 = blockIdx.x*64;        // grid 64
    for (int it = 0; it < 16; it++){
        int e = it*256 + tid;
        int k = e >> 6, c = e & 63;
        t[k*65 + c] = WgOut[(size_t)k*4096 + c0 + c];
    }
    __syncthreads();
    for (int it = 0; it < 16; it++){
        int e = it*256 + tid;
        int c = e >> 6, k = e & 63;
        Wtbf[(size_t)(c0 + c)*64 + k] = f2bf(t[k*65 + c]);
    }
}

// zero the m-tail (304..319) of xT so MFMA reads past NN see 0
__global__ void kZeroTail(unsigned short* __restrict__ xT){
    int gid = blockIdx.x*256 + threadIdx.x;   // 16*64*16 = 16384
    int mo = gid & 15, c = (gid >> 4) & 63, b = gid >> 10;
    xT[((size_t)b*64 + c)*320 + 304 + mo] = 0;
}

__global__ void kInit(const float* __restrict__ ca,
                      const float* __restrict__ hW, const float* __restrict__ hb,
                      const float* __restrict__ zW, const float* __restrict__ zb,
                      float* __restrict__ h, float* __restrict__ z){
    int gid = blockIdx.x*256 + threadIdx.x;   // exactly 314368
    int t = gid & 63;
    int bn = gid >> 6;
    float x0 = ca[bn*NI*2 + 0];
    float x1 = ca[bn*NI*2 + 1];
    h[gid] = x0*hW[t] + x1*hW[64 + t] + hb[t];
    z[gid] = x0*zW[t] + x1*zW[64 + t] + zb[t];
}

// ---------- K1: stage input, func_f MLP, kh, g-input x ----------
// one wave per (b,n); no block barriers (own-wave LDS slices only).
// 4-way split accumulators break the 64-FMA dependent chains.
__global__ __launch_bounds__(256) void K1(
    float* __restrict__ h, const float* __restrict__ z,
    float* __restrict__ kh, const float* __restrict__ kz,
    float* __restrict__ acch, unsigned short* __restrict__ xbf,
    unsigned short* __restrict__ xT,
    const float* __restrict__ Cb, const float* __restrict__ Cc, const float* __restrict__ Cd,
    const float* __restrict__ WfIn, const float* __restrict__ fbIn,
    const float* __restrict__ WfMid, const float* __restrict__ fbMid,
    const float* __restrict__ WfOut, const float* __restrict__ fbOut,
    const float* __restrict__ WgIn, const float* __restrict__ gbIn,
    int stage, float acoef, int idx, float frac)
{
    __shared__ float4 bufA[4][16];
    __shared__ float4 bufB[4][16];
    __shared__ float4 bufZ[4][16];
    int tid = threadIdx.x;
    int wv = tid >> 6;
    int lane = tid & 63;
    int bn = blockIdx.x*4 + wv;            // b*307 + n
    int base = bn*64 + lane;
    unsigned ub = (unsigned)bn / 307u;
    int b = (int)ub;
    int n = bn - b*307;

    float hv = h[base];
    float zv = z[base];
    float sih = hv, siz = zv;
    if (stage > 0){ sih += acoef * kh[base]; siz += acoef * kz[base]; }
    ((float*)&bufA[wv][0])[lane] = sih;
    ((float*)&bufZ[wv][0])[lane] = siz;

    // u1 = relu(sih @ WfIn + fbIn), 4 partial chains
    float a0 = fbIn[lane], a1 = 0.f, a2 = 0.f, a3 = 0.f;
#pragma unroll
    for (int k4 = 0; k4 < 16; k4 += 2){
        float4 s4 = bufA[wv][k4];
        float4 s5 = bufA[wv][k4+1];
        int k = k4*4;
        a0 += s4.x*WfIn[(k+0)*64 + lane];
        a1 += s4.y*WfIn[(k+1)*64 + lane];
        a2 += s4.z*WfIn[(k+2)*64 + lane];
        a3 += s4.w*WfIn[(k+3)*64 + lane];
        a0 += s5.x*WfIn[(k+4)*64 + lane];
        a1 += s5.y*WfIn[(k+5)*64 + lane];
        a2 += s5.z*WfIn[(k+6)*64 + lane];
        a3 += s5.w*WfIn[(k+7)*64 + lane];
    }
    float u = fmaxf((a0 + a1) + (a2 + a3), 0.f);
    ((float*)&bufB[wv][0])[lane] = u;

    // u2 = relu(u1 @ WfMid + fbMid)
    float c0_ = fbMid[lane], c1_ = 0.f, c2_ = 0.f, c3_ = 0.f;
#pragma unroll
    for (int k4 = 0; k4 < 16; k4 += 2){
        float4 s4 = bufB[wv][k4];
        float4 s5 = bufB[wv][k4+1];
        int k = k4*4;
        c0_ += s4.x*WfMid[(k+0)*64 + lane];
        c1_ += s4.y*WfMid[(k+1)*64 + lane];
        c2_ += s4.z*WfMid[(k+2)*64 + lane];
        c3_ += s4.w*WfMid[(k+3)*64 + lane];
        c0_ += s5.x*WfMid[(k+4)*64 + lane];
        c1_ += s5.y*WfMid[(k+5)*64 + lane];
        c2_ += s5.z*WfMid[(k+6)*64 + lane];
        c3_ += s5.w*WfMid[(k+7)*64 + lane];
    }
    float u2v = fmaxf((c0_ + c1_) + (c2_ + c3_), 0.f);
    ((float*)&bufA[wv][0])[lane] = u2v;

    // f_v + x, split chains by k4 parity
    float f0a = fbOut[lane*2 + 0], f0b = 0.f;
    float f1a = fbOut[lane*2 + 1], f1b = 0.f;
    float xa = gbIn[lane], xb = 0.f;
#pragma unroll
    for (int k4 = 0; k4 < 16; k4 += 2){
        float4 s4 = bufA[wv][k4];
        float4 z4 = bufZ[wv][k4];
        float4 s5 = bufA[wv][k4+1];
        float4 z5 = bufZ[wv][k4+1];
        int k = k4*4;
        f0a += s4.x*WfOut[(k+0)*128 + lane*2+0]; f1a += s4.x*WfOut[(k+0)*128 + lane*2+1];
        f0b += s4.y*WfOut[(k+1)*128 + lane*2+0]; f1b += s4.y*WfOut[(k+1)*128 + lane*2+1];
        f0a += s4.z*WfOut[(k+2)*128 + lane*2+0]; f1a += s4.z*WfOut[(k+2)*128 + lane*2+1];
        f0b += s4.w*WfOut[(k+3)*128 + lane*2+0]; f1b += s4.w*WfOut[(k+3)*128 + lane*2+1];
        f0a += s5.x*WfOut[(k+4)*128 + lane*2+0]; f1a += s5.x*WfOut[(k+4)*128 + lane*2+1];
        f0b += s5.y*WfOut[(k+5)*128 + lane*2+0]; f1b += s5.y*WfOut[(k+5)*128 + lane*2+1];
        f0a += s5.z*WfOut[(k+6)*128 + lane*2+0]; f1a += s5.z*WfOut[(k+6)*128 + lane*2+1];
        f0b += s5.w*WfOut[(k+7)*128 + lane*2+0]; f1b += s5.w*WfOut[(k+7)*128 + lane*2+1];
        xa += z4.x*WgIn[(k+0)*64 + lane];
        xb += z4.y*WgIn[(k+1)*64 + lane];
        xa += z4.z*WgIn[(k+2)*64 + lane];
        xb += z4.w*WgIn[(k+3)*64 + lane];
        xa += z5.x*WgIn[(k+4)*64 + lane];
        xb += z5.y*WgIn[(k+5)*64 + lane];
        xa += z5.z*WgIn[(k+6)*64 + lane];
        xb += z5.w*WgIn[(k+7)*64 + lane];
    }
    float f0 = tanh_fast(f0a + f0b);
    float f1 = tanh_fast(f1a + f1b);
    float xv = fmaxf(xa + xb, 0.f);

    int cb = (bn*NI + idx)*2;
    float b0 = Cb[cb], b1 = Cb[cb+1];
    float c0 = Cc[cb], c1 = Cc[cb+1];
    float d0 = Cd[cb], d1 = Cd[cb+1];
    float dx0 = b0 + (c0 + d0*frac)*frac;
    float dx1 = b1 + (c1 + d1*frac)*frac;

    float khv = f0*dx0 + f1*dx1;
    kh[base] = khv;
    if (stage == 0)      acch[base] = khv;
    else if (stage < 3)  acch[base] += 2.f*khv;
    else                 h[base] = hv + (1.f/6.f)*(acch[base] + khv);

    unsigned short xbfv = f2bf(xv);
    xbf[((size_t)n*16 + b)*64 + lane] = xbfv;          // node-major for Y-compute
    xT[((size_t)b*64 + lane)*320 + n] = xbfv;          // [b][c][m] for KXG fragments
}

// ---------- KXG: xg = A @ x per batch, pure-MFMA, no LDS. grid 320 ----------
__global__ __launch_bounds__(256) void KXG(
    const unsigned short* __restrict__ xT, const unsigned short* __restrict__ Abf,
    unsigned short* __restrict__ xgbf)
{
    int tid = threadIdx.x, lane = tid & 63, wv = tid >> 6;
    int quad = lane >> 4, l15 = lane & 15;
    int b = blockIdx.x / 20, nt = blockIdx.x % 20;
    int n0 = nt*16;

    f32x4 acc = {0.f,0.f,0.f,0.f};
#pragma unroll
    for (int mt = 0; mt < 10; mt++){
        bf16x8 a  = *(const bf16x8*)(Abf + (size_t)(n0 + l15)*320 + mt*32 + quad*8);
        bf16x8 bb = *(const bf16x8*)(xT + ((size_t)b*64 + wv*16 + l15)*320 + mt*32 + quad*8);
        acc = __builtin_amdgcn_mfma_f32_16x16x32_bf16(a, bb, acc, 0, 0, 0);
    }
    // D[n'=quad*4+r][c'=l15], wave wv owns c-tile wv*16
#pragma unroll
    for (int r = 0; r < 4; r++){
        int n = n0 + quad*4 + r;
        xgbf[((size_t)n*16 + b)*64 + wv*16 + l15] = f2bf(acc[r]);
    }
}

// ---------- K2g: per-node Y (MFMA) + Wt@Y^T from global + tanh*kh contraction ----------
// grid 77*16 = 1232, barrier-free; 5 blocks/CU (all co-resident in one round)
__global__ __launch_bounds__(256, 5) void K2g(
    float* __restrict__ z, const float* __restrict__ kh,
    float* __restrict__ kz, float* __restrict__ accz,
    const unsigned short* __restrict__ xbf, const unsigned short* __restrict__ xgbf,
    const unsigned short* __restrict__ agcWt, const float* __restrict__ agcb,
    const unsigned short* __restrict__ Wtbf, const float* __restrict__ gbOut,
    int stage)
{
    __shared__ unsigned short Ybf[4*16*72];   // [w][b][k] pad 72 (own-wave rows)
    __shared__ float dzl[4*16*5];             // [w][b][il] pad 5 (own-wave rows)
    int tid = threadIdx.x, lane = tid & 63, wv = tid >> 6;
    int quad = lane >> 4, l15 = lane & 15;
    int nt = blockIdx.x >> 4, cg = blockIdx.x & 15;
    int n0 = nt*4;
    int nw = n0 + wv;
    int n = nw < NN ? nw : NN-1;
    int C0 = cg*256;

    // kh for (b=l15, node n): full 64-float row split over (c,quad) float4s
    float4 khr[4];
#pragma unroll
    for (int c = 0; c < 4; c++)
        khr[c] = *(const float4*)(kh + ((size_t)l15*NN + n)*64 + c*16 + quad*4);

    // Y-compute: Y_n[b][o] = relu(Xcat_n @ agcWt_n + agcb_n)
    const size_t xrow = ((size_t)n*16 + l15)*64;
#pragma unroll
    for (int ot = 0; ot < 4; ot++){
        f32x4 acc = {0.f,0.f,0.f,0.f};
#pragma unroll
        for (int kt = 0; kt < 4; kt++){
            bf16x8 a;
            if (kt < 2) a = *(const bf16x8*)(xbf  + xrow + kt*32 + quad*8);
            else        a = *(const bf16x8*)(xgbf + xrow + (kt-2)*32 + quad*8);
            bf16x8 bb = *(const bf16x8*)(agcWt + ((size_t)n*64 + ot*16 + l15)*128 + kt*32 + quad*8);
            acc = __builtin_amdgcn_mfma_f32_16x16x32_bf16(a, bb, acc, 0, 0, 0);
        }
        float gb = agcb[n*64 + ot*16 + l15];
#pragma unroll
        for (int r = 0; r < 4; r++){
            float v = fmaxf(acc[r] + gb, 0.f);
            Ybf[(wv*16 + quad*4 + r)*72 + ot*16 + l15] = f2bf(v);
        }
    }
    // own-wave LDS only -> no __syncthreads anywhere

    // GEMM cols C0..C0+255 from global Wtbf (L2-hot); fuse tanh, *kh, j-reduction
#pragma unroll
    for (int i4 = 0; i4 < 4; i4++){
        float pacc = 0.f;
#pragma unroll
        for (int c4 = 0; c4 < 4; c4++){
            int ct = i4*4 + c4;
            f32x4 acc = {0.f,0.f,0.f,0.f};
#pragma unroll
            for (int kt = 0; kt < 2; kt++){
                bf16x8 a  = *(const bf16x8*)(Wtbf + (size_t)(C0 + ct*16 + l15)*64 + kt*32 + quad*8);
                bf16x8 bb = *(const bf16x8*)(Ybf + (wv*16 + l15)*72 + kt*32 + quad*8);
                acc = __builtin_amdgcn_mfma_f32_16x16x32_bf16(a, bb, acc, 0, 0, 0);
            }
            float4 gb4 = *(const float4*)(gbOut + C0 + ct*16 + quad*4);
            float4 kh4 = khr[c4];
            pacc += tanh_fast(acc[0] + gb4.x) * kh4.x
                  + tanh_fast(acc[1] + gb4.y) * kh4.y
                  + tanh_fast(acc[2] + gb4.z) * kh4.z
                  + tanh_fast(acc[3] + gb4.w) * kh4.w;
        }
        pacc += __shfl_xor(pacc, 16, 64);
        pacc += __shfl_xor(pacc, 32, 64);
        if (quad == 0) dzl[(wv*16 + l15)*5 + i4] = pacc;
    }

    // write-out + RK4 z bookkeeping: 4 nodes x 16 b x 4 i = 256 values (own wave w=wv)
    {
        int w = tid >> 6, bb_ = (tid >> 2) & 15, il = tid & 3;
        int nn = n0 + w;
        if (nn < NN){
            size_t addr = ((size_t)bb_*NN + nn)*64 + cg*4 + il;
            float v = dzl[(w*16 + bb_)*5 + il];
            kz[addr] = v;
            if (stage == 0)      accz[addr] = v;
            else if (stage < 3)  accz[addr] += 2.f*v;
            else                 z[addr] += (1.f/6.f)*(accz[addr] + v);
        }
    }
}

// ---------- output ----------
__global__ __launch_bounds__(256) void kOut(const float* __restrict__ z,
                                            const float* __restrict__ convW,
                                            const float* __restrict__ convB,
                                            float* __restrict__ out){
    int gid = blockIdx.x*256 + threadIdx.x;
    if (gid >= NB*NN) return;
    int b = gid / NN, n = gid % NN;
    float zr[64];
    const float4* zp = (const float4*)(z + (size_t)gid*64);
#pragma unroll
    for (int k4 = 0; k4 < 16; k4++){
        float4 v = zp[k4];
        zr[k4*4+0] = v.x; zr[k4*4+1] = v.y; zr[k4*4+2] = v.z; zr[k4*4+3] = v.w;
    }
#pragma unroll
    for (int o = 0; o < 12; o++){
        float acc = convB[o];
#pragma unroll
        for (int hh = 0; hh < 64; hh++) acc += zr[hh]*convW[o*64 + hh];
        out[(b*12 + o)*NN + n] = acc;
    }
}

extern "C" void kernel_launch(void* const* d_in, const int* in_sizes, int n_in,
                              void* d_out, int out_size, void* d_ws, size_t ws_size,
                              hipStream_t stream)
{
    const float* coeff_a = (const float*)d_in[0];
    const float* coeff_b = (const float*)d_in[1];
    const float* coeff_c = (const float*)d_in[2];
    const float* coeff_d = (const float*)d_in[3];
    const float* hW     = (const float*)d_in[5];
    const float* hb     = (const float*)d_in[6];
    const float* zW     = (const float*)d_in[7];
    const float* zb     = (const float*)d_in[8];
    const float* WfIn   = (const float*)d_in[9];
    const float* fbIn   = (const float*)d_in[10];
    const float* WfMid  = (const float*)d_in[11];
    const float* fbMid  = (const float*)d_in[12];
    const float* WfOut  = (const float*)d_in[13];
    const float* fbOut  = (const float*)d_in[14];
    const float* WgIn   = (const float*)d_in[15];
    const float* gbIn   = (const float*)d_in[16];
    const float* gE     = (const float*)d_in[17];
    const float* gWpool = (const float*)d_in[18];
    const float* gbpool = (const float*)d_in[19];
    const float* WgOut  = (const float*)d_in[20];
    const float* gbOut  = (const float*)d_in[21];
    const float* convW  = (const float*)d_in[22];
    const float* convB  = (const float*)d_in[23];

    float* ws = (float*)d_ws;
    unsigned short* Abf   = (unsigned short*)(ws + OFF_ABF);
    unsigned short* agcWt = (unsigned short*)(ws + OFF_AGCWT);
    float*          agcb  = ws + OFF_AGCB;
    unsigned short* Wtbf  = (unsigned short*)(ws + OFF_WT);
    float* h    = ws + OFF_H;
    float* z    = ws + OFF_Z;
    float* kh   = ws + OFF_KH;
    float* kz   = ws + OFF_KZ;
    float* acch = ws + OFF_ACCH;
    float* accz = ws + OFF_ACCZ;
    unsigned short* xbf  = (unsigned short*)(ws + OFF_XBF);
    unsigned short* xgbf = (unsigned short*)(ws + OFF_XGBF);
    unsigned short* xT   = (unsigned short*)(ws + OFF_XT);
    float* out = (float*)d_out;

    kA        <<<320, 64,  0, stream>>>(gE, Abf);
    kAgcWT    <<<NN,  256, 0, stream>>>(gE, gWpool, agcWt);
    kAgcB     <<<77,  256, 0, stream>>>(gE, gbpool, agcb);
    kWt       <<<64,  256, 0, stream>>>(WgOut, Wtbf);
    kZeroTail <<<64,  256, 0, stream>>>(xT);
    kInit     <<<1228,256, 0, stream>>>(coeff_a, hW, hb, zW, zb, h, z);

    const float acoef[4] = {0.f, 0.5f, 0.5f, 1.f};
    for (int step = 0; step < 11; step++){
        for (int s = 0; s < 4; s++){
            int idx; float frac;
            if (s == 0)      { idx = step;     frac = 0.f;  }
            else if (s < 3)  { idx = step;     frac = 0.5f; }
            else if (step<10){ idx = step + 1; frac = 0.f;  }
            else             { idx = 10;       frac = 1.f;  }
            K1 <<<1228, 256, 0, stream>>>(h, z, kh, kz, acch, xbf, xT,
                coeff_b, coeff_c, coeff_d, WfIn, fbIn, WfMid, fbMid,
                WfOut, fbOut, WgIn, gbIn, s, acoef[s], idx, frac);
            KXG<<<320, 256, 0, stream>>>(xT, Abf, xgbf);
            K2g<<<1232, 256, 0, stream>>>(z, kh, kz, accz, xbf, xgbf,
                agcWt, agcb, Wtbf, gbOut, s);
        }
    }
    kOut<<<20, 256, 0, stream>>>(z, convW, convB, out);
}

// Round 6
// 2266.098 us; speedup vs baseline: 1.3762x; 1.3762x over previous
//
#include <hip/hip_runtime.h>

#define NB 16
#define NN 307
#define NI 11

typedef __attribute__((ext_vector_type(8))) short bf16x8;
typedef __attribute__((ext_vector_type(4))) float f32x4;

// ws offsets in FLOAT units
#define OFF_ABF    0u          // 320x320 bf16 = 51200 fl
#define OFF_AGCWT  51200u      // 307*64*128 bf16 = 1257472 fl
#define OFF_AGCB   1308672u    // 307*64 f32 -> pad 20480
#define OFF_WT     1329152u    // 4096*64 bf16 = 131072 fl (seg-swizzled)
#define OFF_H      1460224u    // each state: 16*307*64 = 314368 fl
#define OFF_Z      1774592u
#define OFF_KH     2088960u
#define OFF_KZ     2403328u
#define OFF_ACCH   2717696u
#define OFF_ACCZ   3032064u
#define OFF_XBF    3346432u    // 320*16*64 bf16 = 163840 fl
#define OFF_XGBF   3510272u    // 320*16*64 bf16 = 163840 fl
#define OFF_XT     3674112u    // 16*64*320 bf16 = 163840 fl
#define OFF_YBF    3837952u    // 307*16*64 bf16 = 157184 fl ; end 3995136 fl = 16.0 MB

__device__ __forceinline__ float tanh_fast(float x){
    float e = __expf(2.0f * x);
    return 1.0f - 2.0f * __builtin_amdgcn_rcpf(e + 1.0f);
}
__device__ __forceinline__ unsigned short f2bf(float f){
    unsigned u = __builtin_bit_cast(unsigned, f);
    unsigned r = u + 0x7FFFu + ((u >> 16) & 1u);
    return (unsigned short)(r >> 16);
}

// ---------- precompute ----------

// Abf[n][m] = bf16(softmax(relu(gE gE^T))) padded to 320x320 with zeros
__global__ void kA(const float* __restrict__ gE, unsigned short* __restrict__ Abf){
    int n = blockIdx.x;            // grid 320, 64 threads
    int lane = threadIdx.x;
    if (n >= NN){
#pragma unroll
        for (int ii = 0; ii < 5; ii++) Abf[n*320 + lane + 64*ii] = 0;
        return;
    }
    float en[8];
#pragma unroll
    for (int d = 0; d < 8; d++) en[d] = gE[n*8 + d];
    float vals[5];
    float mx = -1e30f;
#pragma unroll
    for (int ii = 0; ii < 5; ii++){
        int m = lane + 64*ii;
        float v = -1e30f;
        if (m < NN){
            float a = 0.f;
#pragma unroll
            for (int d = 0; d < 8; d++) a += en[d] * gE[m*8 + d];
            v = fmaxf(a, 0.f);
        }
        vals[ii] = v;
        mx = fmaxf(mx, v);
    }
#pragma unroll
    for (int off = 32; off >= 1; off >>= 1) mx = fmaxf(mx, __shfl_xor(mx, off, 64));
    float s = 0.f;
#pragma unroll
    for (int ii = 0; ii < 5; ii++){
        int m = lane + 64*ii;
        if (m < NN){ vals[ii] = __expf(vals[ii] - mx); s += vals[ii]; }
    }
#pragma unroll
    for (int off = 32; off >= 1; off >>= 1) s += __shfl_xor(s, off, 64);
    float inv = 1.f / s;
#pragma unroll
    for (int ii = 0; ii < 5; ii++){
        int m = lane + 64*ii;
        unsigned short v = 0;
        if (m < NN) v = f2bf(vals[ii] * inv);
        Abf[n*320 + m] = v;
    }
}

// agcWt[n][o][k] bf16, k = kk*64+i in [0,128)
__global__ __launch_bounds__(256) void kAgcWT(const float* __restrict__ gE,
                                              const float* __restrict__ gWpool,
                                              unsigned short* __restrict__ agcWt){
    __shared__ float t[128*65];
    int tid = threadIdx.x;
    int n = blockIdx.x;            // grid 307
    float ge[8];
#pragma unroll
    for (int d = 0; d < 8; d++) ge[d] = gE[n*8 + d];
    for (int it = 0; it < 32; it++){
        int e = it*256 + tid;      // [0,8192)
        int o = e & 63, i = (e >> 6) & 63, kk = e >> 12;
        float acc = 0.f;
#pragma unroll
        for (int d = 0; d < 8; d++) acc += ge[d] * gWpool[((size_t)(d*2 + kk)*64 + i)*64 + o];
        t[(kk*64 + i)*65 + o] = acc;
    }
    __syncthreads();
    for (int it = 0; it < 32; it++){
        int e = it*256 + tid;
        int k = e & 127, o = e >> 7;
        agcWt[((size_t)n*64 + o)*128 + k] = f2bf(t[k*65 + o]);
    }
}

__global__ void kAgcB(const float* __restrict__ gE, const float* __restrict__ gbpool,
                      float* __restrict__ agcb){
    int gid = blockIdx.x*256 + threadIdx.x;
    if (gid >= NN*64) return;
    int o = gid & 63;
    int n = gid >> 6;
    float acc = 0.f;
#pragma unroll
    for (int d = 0; d < 8; d++) acc += gE[n*8 + d] * gbpool[d*64 + o];
    agcb[gid] = acc;
}

// Wt_sw[col][seg'] bf16 : transpose of WgOut with 16B-seg swizzle seg' = seg ^ (col&7)
// so K2g's LDS a-frag ds_read_b128 is bank-conflict-free without padding (DMA needs contiguous)
__global__ __launch_bounds__(256) void kWt(const float* __restrict__ WgOut,
                                           unsigned short* __restrict__ Wt_sw){
    __shared__ float t[64*65];
    int tid = threadIdx.x;
    int c0 = blockIdx.x*64;        // grid 64
    for (int it = 0; it < 16; it++){
        int e = it*256 + tid;
        int k = e >> 6, c = e & 63;
        t[k*65 + c] = WgOut[(size_t)k*4096 + c0 + c];
    }
    __syncthreads();
    for (int it = 0; it < 16; it++){
        int e = it*256 + tid;
        int c = e >> 6, k = e & 63;
        int ks = ((((k >> 3) ^ (c & 7)) << 3) | (k & 7));
        Wt_sw[(size_t)(c0 + c)*64 + ks] = f2bf(t[k*65 + c]);
    }
}

// zero the m-tail (304..319) of xT so MFMA reads past NN see 0
__global__ void kZeroTail(unsigned short* __restrict__ xT){
    int gid = blockIdx.x*256 + threadIdx.x;   // 16*64*16 = 16384
    int mo = gid & 15, c = (gid >> 4) & 63, b = gid >> 10;
    xT[((size_t)b*64 + c)*320 + 304 + mo] = 0;
}

__global__ void kInit(const float* __restrict__ ca,
                      const float* __restrict__ hW, const float* __restrict__ hb,
                      const float* __restrict__ zW, const float* __restrict__ zb,
                      float* __restrict__ h, float* __restrict__ z){
    int gid = blockIdx.x*256 + threadIdx.x;   // exactly 314368
    int t = gid & 63;
    int bn = gid >> 6;
    float x0 = ca[bn*NI*2 + 0];
    float x1 = ca[bn*NI*2 + 1];
    h[gid] = x0*hW[t] + x1*hW[64 + t] + hb[t];
    z[gid] = x0*zW[t] + x1*zW[64 + t] + zb[t];
}

// ---------- K1: stage input, func_f MLP, kh, g-input x ----------
__global__ __launch_bounds__(256) void K1(
    float* __restrict__ h, const float* __restrict__ z,
    float* __restrict__ kh, const float* __restrict__ kz,
    float* __restrict__ acch, unsigned short* __restrict__ xbf,
    unsigned short* __restrict__ xT,
    const float* __restrict__ Cb, const float* __restrict__ Cc, const float* __restrict__ Cd,
    const float* __restrict__ WfIn, const float* __restrict__ fbIn,
    const float* __restrict__ WfMid, const float* __restrict__ fbMid,
    const float* __restrict__ WfOut, const float* __restrict__ fbOut,
    const float* __restrict__ WgIn, const float* __restrict__ gbIn,
    int stage, float acoef, int idx, float frac)
{
    __shared__ float4 bufA[4][16];
    __shared__ float4 bufB[4][16];
    __shared__ float4 bufZ[4][16];
    int tid = threadIdx.x;
    int wv = tid >> 6;
    int lane = tid & 63;
    int bn = blockIdx.x*4 + wv;            // b*307 + n
    int base = bn*64 + lane;
    unsigned ub = (unsigned)bn / 307u;
    int b = (int)ub;
    int n = bn - b*307;

    float hv = h[base];
    float zv = z[base];
    float sih = hv, siz = zv;
    if (stage > 0){ sih += acoef * kh[base]; siz += acoef * kz[base]; }
    ((float*)&bufA[wv][0])[lane] = sih;
    ((float*)&bufZ[wv][0])[lane] = siz;

    float a0 = fbIn[lane], a1 = 0.f, a2 = 0.f, a3 = 0.f;
#pragma unroll
    for (int k4 = 0; k4 < 16; k4 += 2){
        float4 s4 = bufA[wv][k4];
        float4 s5 = bufA[wv][k4+1];
        int k = k4*4;
        a0 += s4.x*WfIn[(k+0)*64 + lane];
        a1 += s4.y*WfIn[(k+1)*64 + lane];
        a2 += s4.z*WfIn[(k+2)*64 + lane];
        a3 += s4.w*WfIn[(k+3)*64 + lane];
        a0 += s5.x*WfIn[(k+4)*64 + lane];
        a1 += s5.y*WfIn[(k+5)*64 + lane];
        a2 += s5.z*WfIn[(k+6)*64 + lane];
        a3 += s5.w*WfIn[(k+7)*64 + lane];
    }
    float u = fmaxf((a0 + a1) + (a2 + a3), 0.f);
    ((float*)&bufB[wv][0])[lane] = u;

    float c0_ = fbMid[lane], c1_ = 0.f, c2_ = 0.f, c3_ = 0.f;
#pragma unroll
    for (int k4 = 0; k4 < 16; k4 += 2){
        float4 s4 = bufB[wv][k4];
        float4 s5 = bufB[wv][k4+1];
        int k = k4*4;
        c0_ += s4.x*WfMid[(k+0)*64 + lane];
        c1_ += s4.y*WfMid[(k+1)*64 + lane];
        c2_ += s4.z*WfMid[(k+2)*64 + lane];
        c3_ += s4.w*WfMid[(k+3)*64 + lane];
        c0_ += s5.x*WfMid[(k+4)*64 + lane];
        c1_ += s5.y*WfMid[(k+5)*64 + lane];
        c2_ += s5.z*WfMid[(k+6)*64 + lane];
        c3_ += s5.w*WfMid[(k+7)*64 + lane];
    }
    float u2v = fmaxf((c0_ + c1_) + (c2_ + c3_), 0.f);
    ((float*)&bufA[wv][0])[lane] = u2v;

    float f0a = fbOut[lane*2 + 0], f0b = 0.f;
    float f1a = fbOut[lane*2 + 1], f1b = 0.f;
    float xa = gbIn[lane], xb = 0.f;
#pragma unroll
    for (int k4 = 0; k4 < 16; k4 += 2){
        float4 s4 = bufA[wv][k4];
        float4 z4 = bufZ[wv][k4];
        float4 s5 = bufA[wv][k4+1];
        float4 z5 = bufZ[wv][k4+1];
        int k = k4*4;
        f0a += s4.x*WfOut[(k+0)*128 + lane*2+0]; f1a += s4.x*WfOut[(k+0)*128 + lane*2+1];
        f0b += s4.y*WfOut[(k+1)*128 + lane*2+0]; f1b += s4.y*WfOut[(k+1)*128 + lane*2+1];
        f0a += s4.z*WfOut[(k+2)*128 + lane*2+0]; f1a += s4.z*WfOut[(k+2)*128 + lane*2+1];
        f0b += s4.w*WfOut[(k+3)*128 + lane*2+0]; f1b += s4.w*WfOut[(k+3)*128 + lane*2+1];
        f0a += s5.x*WfOut[(k+4)*128 + lane*2+0]; f1a += s5.x*WfOut[(k+4)*128 + lane*2+1];
        f0b += s5.y*WfOut[(k+5)*128 + lane*2+0]; f1b += s5.y*WfOut[(k+5)*128 + lane*2+1];
        f0a += s5.z*WfOut[(k+6)*128 + lane*2+0]; f1a += s5.z*WfOut[(k+6)*128 + lane*2+1];
        f0b += s5.w*WfOut[(k+7)*128 + lane*2+0]; f1b += s5.w*WfOut[(k+7)*128 + lane*2+1];
        xa += z4.x*WgIn[(k+0)*64 + lane];
        xb += z4.y*WgIn[(k+1)*64 + lane];
        xa += z4.z*WgIn[(k+2)*64 + lane];
        xb += z4.w*WgIn[(k+3)*64 + lane];
        xa += z5.x*WgIn[(k+4)*64 + lane];
        xb += z5.y*WgIn[(k+5)*64 + lane];
        xa += z5.z*WgIn[(k+6)*64 + lane];
        xb += z5.w*WgIn[(k+7)*64 + lane];
    }
    float f0 = tanh_fast(f0a + f0b);
    float f1 = tanh_fast(f1a + f1b);
    float xv = fmaxf(xa + xb, 0.f);

    int cb = (bn*NI + idx)*2;
    float b0 = Cb[cb], b1 = Cb[cb+1];
    float c0 = Cc[cb], c1 = Cc[cb+1];
    float d0 = Cd[cb], d1 = Cd[cb+1];
    float dx0 = b0 + (c0 + d0*frac)*frac;
    float dx1 = b1 + (c1 + d1*frac)*frac;

    float khv = f0*dx0 + f1*dx1;
    kh[base] = khv;
    if (stage == 0)      acch[base] = khv;
    else if (stage < 3)  acch[base] += 2.f*khv;
    else                 h[base] = hv + (1.f/6.f)*(acch[base] + khv);

    unsigned short xbfv = f2bf(xv);
    xbf[((size_t)n*16 + b)*64 + lane] = xbfv;          // node-major for KY
    xT[((size_t)b*64 + lane)*320 + n] = xbfv;          // [b][c][m] for KXG fragments
}

// ---------- KXG: xg = A @ x per batch, pure-MFMA, no LDS. grid 320 ----------
__global__ __launch_bounds__(256) void KXG(
    const unsigned short* __restrict__ xT, const unsigned short* __restrict__ Abf,
    unsigned short* __restrict__ xgbf)
{
    int tid = threadIdx.x, lane = tid & 63, wv = tid >> 6;
    int quad = lane >> 4, l15 = lane & 15;
    int b = blockIdx.x / 20, nt = blockIdx.x % 20;
    int n0 = nt*16;

    f32x4 acc = {0.f,0.f,0.f,0.f};
#pragma unroll
    for (int mt = 0; mt < 10; mt++){
        bf16x8 a  = *(const bf16x8*)(Abf + (size_t)(n0 + l15)*320 + mt*32 + quad*8);
        bf16x8 bb = *(const bf16x8*)(xT + ((size_t)b*64 + wv*16 + l15)*320 + mt*32 + quad*8);
        acc = __builtin_amdgcn_mfma_f32_16x16x32_bf16(a, bb, acc, 0, 0, 0);
    }
#pragma unroll
    for (int r = 0; r < 4; r++){
        int n = n0 + quad*4 + r;
        xgbf[((size_t)n*16 + b)*64 + wv*16 + l15] = f2bf(acc[r]);
    }
}

// ---------- KY: Y_n = relu([x,xg]_n @ agcWt_n + agcb_n), once per node. grid 77 ----------
__global__ __launch_bounds__(256) void KY(
    const unsigned short* __restrict__ xbf, const unsigned short* __restrict__ xgbf,
    const unsigned short* __restrict__ agcWt, const float* __restrict__ agcb,
    unsigned short* __restrict__ Ybf_g)
{
    int tid = threadIdx.x, lane = tid & 63, wv = tid >> 6;
    int quad = lane >> 4, l15 = lane & 15;
    int nw = blockIdx.x*4 + wv;
    if (nw >= NN) return;
    const size_t xrow = ((size_t)nw*16 + l15)*64;
    bf16x8 a[4];
    a[0] = *(const bf16x8*)(xbf  + xrow + 0  + quad*8);
    a[1] = *(const bf16x8*)(xbf  + xrow + 32 + quad*8);
    a[2] = *(const bf16x8*)(xgbf + xrow + 0  + quad*8);
    a[3] = *(const bf16x8*)(xgbf + xrow + 32 + quad*8);
#pragma unroll
    for (int ot = 0; ot < 4; ot++){
        f32x4 acc = {0.f,0.f,0.f,0.f};
#pragma unroll
        for (int kt = 0; kt < 4; kt++){
            bf16x8 bbb = *(const bf16x8*)(agcWt + ((size_t)nw*64 + ot*16 + l15)*128 + kt*32 + quad*8);
            acc = __builtin_amdgcn_mfma_f32_16x16x32_bf16(a[kt], bbb, acc, 0, 0, 0);
        }
        float gb = agcb[nw*64 + ot*16 + l15];
#pragma unroll
        for (int r = 0; r < 4; r++)
            Ybf_g[((size_t)nw*16 + quad*4 + r)*64 + ot*16 + l15] = f2bf(fmaxf(acc[r] + gb, 0.f));
    }
}

// ---------- K2g: streaming GEMM Wt@Y^T from DMA-staged LDS + tanh*kh contraction ----------
// grid 77*16 = 1232 : nt = blk>>4 (4 nodes), cg = blk&15 (256 cols); 4 blocks/CU
__global__ __launch_bounds__(256, 4) void K2g(
    float* __restrict__ z, const float* __restrict__ kh,
    float* __restrict__ kz, float* __restrict__ accz,
    const unsigned short* __restrict__ Ybf_g,
    const unsigned short* __restrict__ Wt_sw, const float* __restrict__ gbOut,
    int stage)
{
    __shared__ unsigned short WtL[256*64];    // 32 KB, source-swizzled rows
    __shared__ float dzl[4*16*5];             // [w][b][il] pad 5 (own-wave rows)
    int tid = threadIdx.x, lane = tid & 63, wv = tid >> 6;
    int quad = lane >> 4, l15 = lane & 15;
    int nt = blockIdx.x >> 4, cg = blockIdx.x & 15;
    int n0 = nt*4;
    int nw = n0 + wv;
    int n = nw < NN ? nw : NN-1;
    int C0 = cg*256;

    // DMA the 256x64 Wt slice -> LDS (VGPR-free, deep queue)
#pragma unroll
    for (int it = 0; it < 8; it++){
        int seg = it*256 + wv*64 + lane;
        const unsigned short* src = Wt_sw + (size_t)C0*64 + (size_t)seg*8;
        __builtin_amdgcn_global_load_lds(
            (const __attribute__((address_space(1))) void*)src,
            (__attribute__((address_space(3))) void*)(WtL + (it*256 + wv*64)*8),
            16, 0, 0);
    }

    // hoisted ct-invariant operands: kh row (b=l15) and Y B-fragments
    float4 khr[4];
#pragma unroll
    for (int c = 0; c < 4; c++)
        khr[c] = *(const float4*)(kh + ((size_t)l15*NN + n)*64 + c*16 + quad*4);
    bf16x8 bb0 = *(const bf16x8*)(Ybf_g + ((size_t)n*16 + l15)*64 + 0  + quad*8);
    bf16x8 bb1 = *(const bf16x8*)(Ybf_g + ((size_t)n*16 + l15)*64 + 32 + quad*8);

    __syncthreads();   // drains DMA (vmcnt 0) + makes WtL visible to all waves

    int sw = l15 & 7;
#pragma unroll
    for (int i4 = 0; i4 < 4; i4++){
        float pacc = 0.f;
#pragma unroll
        for (int c4 = 0; c4 < 4; c4++){
            int ct = i4*4 + c4;
            int row = ct*16 + l15;
            f32x4 acc = {0.f,0.f,0.f,0.f};
            bf16x8 a0 = *(const bf16x8*)(WtL + row*64 + (((quad)     ^ sw) << 3));
            acc = __builtin_amdgcn_mfma_f32_16x16x32_bf16(a0, bb0, acc, 0, 0, 0);
            bf16x8 a1 = *(const bf16x8*)(WtL + row*64 + (((4 + quad) ^ sw) << 3));
            acc = __builtin_amdgcn_mfma_f32_16x16x32_bf16(a1, bb1, acc, 0, 0, 0);
            float4 gb4 = *(const float4*)(gbOut + C0 + ct*16 + quad*4);
            float4 kh4 = khr[c4];
            pacc += tanh_fast(acc[0] + gb4.x) * kh4.x
                  + tanh_fast(acc[1] + gb4.y) * kh4.y
                  + tanh_fast(acc[2] + gb4.z) * kh4.z
                  + tanh_fast(acc[3] + gb4.w) * kh4.w;
        }
        pacc += __shfl_xor(pacc, 16, 64);
        pacc += __shfl_xor(pacc, 32, 64);
        if (quad == 0) dzl[(wv*16 + l15)*5 + i4] = pacc;
    }

    // write-out + RK4 z bookkeeping (own-wave dzl rows)
    {
        int w = tid >> 6, bb_ = (tid >> 2) & 15, il = tid & 3;
        int nn = n0 + w;
        if (nn < NN){
            size_t addr = ((size_t)bb_*NN + nn)*64 + cg*4 + il;
            float v = dzl[(w*16 + bb_)*5 + il];
            kz[addr] = v;
            if (stage == 0)      accz[addr] = v;
            else if (stage < 3)  accz[addr] += 2.f*v;
            else                 z[addr] += (1.f/6.f)*(accz[addr] + v);
        }
    }
}

// ---------- output ----------
__global__ __launch_bounds__(256) void kOut(const float* __restrict__ z,
                                            const float* __restrict__ convW,
                                            const float* __restrict__ convB,
                                            float* __restrict__ out){
    int gid = blockIdx.x*256 + threadIdx.x;
    if (gid >= NB*NN) return;
    int b = gid / NN, n = gid % NN;
    float zr[64];
    const float4* zp = (const float4*)(z + (size_t)gid*64);
#pragma unroll
    for (int k4 = 0; k4 < 16; k4++){
        float4 v = zp[k4];
        zr[k4*4+0] = v.x; zr[k4*4+1] = v.y; zr[k4*4+2] = v.z; zr[k4*4+3] = v.w;
    }
#pragma unroll
    for (int o = 0; o < 12; o++){
        float acc = convB[o];
#pragma unroll
        for (int hh = 0; hh < 64; hh++) acc += zr[hh]*convW[o*64 + hh];
        out[(b*12 + o)*NN + n] = acc;
    }
}

extern "C" void kernel_launch(void* const* d_in, const int* in_sizes, int n_in,
                              void* d_out, int out_size, void* d_ws, size_t ws_size,
                              hipStream_t stream)
{
    const float* coeff_a = (const float*)d_in[0];
    const float* coeff_b = (const float*)d_in[1];
    const float* coeff_c = (const float*)d_in[2];
    const float* coeff_d = (const float*)d_in[3];
    const float* hW     = (const float*)d_in[5];
    const float* hb     = (const float*)d_in[6];
    const float* zW     = (const float*)d_in[7];
    const float* zb     = (const float*)d_in[8];
    const float* WfIn   = (const float*)d_in[9];
    const float* fbIn   = (const float*)d_in[10];
    const float* WfMid  = (const float*)d_in[11];
    const float* fbMid  = (const float*)d_in[12];
    const float* WfOut  = (const float*)d_in[13];
    const float* fbOut  = (const float*)d_in[14];
    const float* WgIn   = (const float*)d_in[15];
    const float* gbIn   = (const float*)d_in[16];
    const float* gE     = (const float*)d_in[17];
    const float* gWpool = (const float*)d_in[18];
    const float* gbpool = (const float*)d_in[19];
    const float* WgOut  = (const float*)d_in[20];
    const float* gbOut  = (const float*)d_in[21];
    const float* convW  = (const float*)d_in[22];
    const float* convB  = (const float*)d_in[23];

    float* ws = (float*)d_ws;
    unsigned short* Abf   = (unsigned short*)(ws + OFF_ABF);
    unsigned short* agcWt = (unsigned short*)(ws + OFF_AGCWT);
    float*          agcb  = ws + OFF_AGCB;
    unsigned short* Wt_sw = (unsigned short*)(ws + OFF_WT);
    float* h    = ws + OFF_H;
    float* z    = ws + OFF_Z;
    float* kh   = ws + OFF_KH;
    float* kz   = ws + OFF_KZ;
    float* acch = ws + OFF_ACCH;
    float* accz = ws + OFF_ACCZ;
    unsigned short* xbf  = (unsigned short*)(ws + OFF_XBF);
    unsigned short* xgbf = (unsigned short*)(ws + OFF_XGBF);
    unsigned short* xT   = (unsigned short*)(ws + OFF_XT);
    unsigned short* Ybf  = (unsigned short*)(ws + OFF_YBF);
    float* out = (float*)d_out;

    kA        <<<320, 64,  0, stream>>>(gE, Abf);
    kAgcWT    <<<NN,  256, 0, stream>>>(gE, gWpool, agcWt);
    kAgcB     <<<77,  256, 0, stream>>>(gE, gbpool, agcb);
    kWt       <<<64,  256, 0, stream>>>(WgOut, Wt_sw);
    kZeroTail <<<64,  256, 0, stream>>>(xT);
    kInit     <<<1228,256, 0, stream>>>(coeff_a, hW, hb, zW, zb, h, z);

    const float acoef[4] = {0.f, 0.5f, 0.5f, 1.f};
    for (int step = 0; step < 11; step++){
        for (int s = 0; s < 4; s++){
            int idx; float frac;
            if (s == 0)      { idx = step;     frac = 0.f;  }
            else if (s < 3)  { idx = step;     frac = 0.5f; }
            else if (step<10){ idx = step + 1; frac = 0.f;  }
            else             { idx = 10;       frac = 1.f;  }
            K1 <<<1228, 256, 0, stream>>>(h, z, kh, kz, acch, xbf, xT,
                coeff_b, coeff_c, coeff_d, WfIn, fbIn, WfMid, fbMid,
                WfOut, fbOut, WgIn, gbIn, s, acoef[s], idx, frac);
            KXG<<<320, 256, 0, stream>>>(xT, Abf, xgbf);
            KY <<<77,  256, 0, stream>>>(xbf, xgbf, agcWt, agcb, Ybf);
            K2g<<<1232, 256, 0, stream>>>(z, kh, kz, accz, Ybf,
                Wt_sw, gbOut, s);
        }
    }
    kOut<<<20, 256, 0, stream>>>(z, convW, convB, out);
}